// Round 3
// baseline (421.036 us; speedup 1.0000x reference)
//
#include <hip/hip_runtime.h>
#include <hip/hip_bf16.h>

#define N_ROWS 131072
#define D_IN   512
#define DK     64

typedef short bf16x8 __attribute__((ext_vector_type(8)));
typedef float f32x4  __attribute__((ext_vector_type(4)));

__device__ __forceinline__ unsigned short f2bf(float f) {
    union { float f; unsigned u; } v; v.f = f;
    unsigned r = v.u + 0x7FFFu + ((v.u >> 16) & 1u);   // RNE
    return (unsigned short)(r >> 16);
}
__device__ __forceinline__ float bf2f(unsigned short h) {
    union { unsigned u; float f; } v; v.u = ((unsigned)h) << 16;
    return v.f;
}
__device__ __forceinline__ float phi_f(float x) {
    return x > 0.f ? (x + 1.f) : __expf(x);   // elu(x)+1
}

// ---------------------------------------------------------------- prep ----
// Pack [Wq|Wk|Wv] (each [512][64] f32) into transposed bf16 W_bfT[192][512],
// and zero the final KV/ksum accumulator (4160 f32).
__global__ void la_prep(const float* __restrict__ Wq, const float* __restrict__ Wk,
                        const float* __restrict__ Wv, unsigned short* __restrict__ wbfT,
                        float* __restrict__ finals) {
    int idx = blockIdx.x * 1024 + threadIdx.x;
    if (idx < 4160) finals[idx] = 0.f;
    if (idx < 192 * 512) {
        int cc = idx >> 9;            // 0..191 output feature
        int k  = idx & 511;           // 0..511 input feature
        const float* W = (cc < 64) ? Wq : (cc < 128 ? Wk : Wv);
        wbfT[idx] = f2bf(W[k * DK + (cc & 63)]);
    }
}

// ---------------------------------------------------------------- main ----
// BM=128 rows/block, BK=64, 12 waves = 4 row-groups x 3 sections (Q,K,V).
// Computes C[128][192] = X_tile @ [Wq|Wk|Wv] via bf16 MFMA, then:
//   sec0: Qphi -> global (bf16)
//   sec1: Kphi -> LDS transposed + column sums
//   sec2: V    -> LDS transposed
// then per-block KV partial = KphiT @ V via MFMA, + ksum partial -> ws.
#define XS 72    // X LDS row stride (bf16 elems): 144 B = 9*16 -> 2-way max
#define WSR 72   // W LDS row stride
#define TS 136   // transposed KphiT/VT row stride: 272 B = 17*16

__global__ __launch_bounds__(768) void la_main(
    const float* __restrict__ X, const unsigned short* __restrict__ wbfT,
    unsigned short* __restrict__ qphi, float* __restrict__ part)
{
    __shared__ __align__(16) char smem[46080];
    __shared__ float ksum_lds[64];

    unsigned short* xs  = (unsigned short*)smem;            // [128][72]
    unsigned short* wsm = (unsigned short*)(smem + 18432);  // [192][72]
    unsigned short* kT  = (unsigned short*)smem;            // [64][136] (overlays staging)
    unsigned short* vT  = (unsigned short*)(smem + 17408);  // [64][136]

    const int tid = threadIdx.x;
    const int w   = tid >> 6;
    const int l   = tid & 63;
    const int c   = l & 15;        // lane low: col (B/C) or row (A)
    const int g   = l >> 4;        // lane group
    const int sec = w % 3;         // 0=Q 1=K 2=V
    const int r   = w / 3;         // row group 0..3 (32 rows each)
    const long rowBase = (long)blockIdx.x * 128;

    if (tid < 64) ksum_lds[tid] = 0.f;

    f32x4 acc[2][4];
#pragma unroll
    for (int m = 0; m < 2; ++m)
#pragma unroll
        for (int f = 0; f < 4; ++f) acc[m][f] = (f32x4){0.f, 0.f, 0.f, 0.f};

    for (int kb = 0; kb < D_IN / 64; ++kb) {
        const int k0 = kb * 64;
        // stage X tile: 128x64 f32 -> bf16 LDS (2048 float4 slots)
        for (int i = tid; i < 2048; i += 768) {
            const int rl = i >> 4, c4 = i & 15;
            const float4 xv = *(const float4*)(X + (rowBase + rl) * D_IN + k0 + (c4 << 2));
            const unsigned u0 = (unsigned)f2bf(xv.x) | ((unsigned)f2bf(xv.y) << 16);
            const unsigned u1 = (unsigned)f2bf(xv.z) | ((unsigned)f2bf(xv.w) << 16);
            *(uint2*)(xs + rl * XS + (c4 << 2)) = make_uint2(u0, u1);
        }
        // stage W tile: 192 rows x 64 k (bf16), 16B chunks
        for (int i = tid; i < 1536; i += 768) {
            const int cc = i >> 3, ch = i & 7;
            *(float4*)(wsm + cc * WSR + (ch << 3)) =
                *(const float4*)(wbfT + cc * D_IN + k0 + (ch << 3));
        }
        __syncthreads();
#pragma unroll
        for (int ks = 0; ks < 2; ++ks) {
            const int ko = ks * 32 + g * 8;
            bf16x8 a[2], b[4];
#pragma unroll
            for (int m = 0; m < 2; ++m)
                a[m] = *(const bf16x8*)(xs + (r * 32 + m * 16 + c) * XS + ko);
#pragma unroll
            for (int f = 0; f < 4; ++f)
                b[f] = *(const bf16x8*)(wsm + (sec * 64 + f * 16 + c) * WSR + ko);
#pragma unroll
            for (int m = 0; m < 2; ++m)
#pragma unroll
                for (int f = 0; f < 4; ++f)
                    acc[m][f] = __builtin_amdgcn_mfma_f32_16x16x32_bf16(a[m], b[f], acc[m][f], 0, 0, 0);
        }
        __syncthreads();
    }

    // ---- epilogue: C/D frag mapping col = c + 16f, row = 32r + 16m + 4g + reg
    if (sec == 0) {
#pragma unroll
        for (int m = 0; m < 2; ++m)
#pragma unroll
            for (int f = 0; f < 4; ++f)
#pragma unroll
                for (int reg = 0; reg < 4; ++reg) {
                    const long row = rowBase + r * 32 + m * 16 + g * 4 + reg;
                    qphi[row * DK + f * 16 + c] = f2bf(phi_f(acc[m][f][reg]));
                }
    } else if (sec == 1) {
        float s[4] = {0.f, 0.f, 0.f, 0.f};
#pragma unroll
        for (int m = 0; m < 2; ++m)
#pragma unroll
            for (int f = 0; f < 4; ++f) {
                float p0 = phi_f(acc[m][f][0]), p1 = phi_f(acc[m][f][1]);
                float p2 = phi_f(acc[m][f][2]), p3 = phi_f(acc[m][f][3]);
                s[f] += p0 + p1 + p2 + p3;
                const int col = f * 16 + c;
                const int row0 = r * 32 + m * 16 + g * 4;
                *(unsigned*)(kT + col * TS + row0)     = (unsigned)f2bf(p0) | ((unsigned)f2bf(p1) << 16);
                *(unsigned*)(kT + col * TS + row0 + 2) = (unsigned)f2bf(p2) | ((unsigned)f2bf(p3) << 16);
            }
#pragma unroll
        for (int f = 0; f < 4; ++f) {
            s[f] += __shfl_xor(s[f], 16);
            s[f] += __shfl_xor(s[f], 32);
        }
        if (l < 16)
#pragma unroll
            for (int f = 0; f < 4; ++f) atomicAdd(&ksum_lds[f * 16 + c], s[f]);
    } else {
#pragma unroll
        for (int m = 0; m < 2; ++m)
#pragma unroll
            for (int f = 0; f < 4; ++f) {
                const int col = f * 16 + c;
                const int row0 = r * 32 + m * 16 + g * 4;
                *(unsigned*)(vT + col * TS + row0) =
                    (unsigned)f2bf(acc[m][f][0]) | ((unsigned)f2bf(acc[m][f][1]) << 16);
                *(unsigned*)(vT + col * TS + row0 + 2) =
                    (unsigned)f2bf(acc[m][f][2]) | ((unsigned)f2bf(acc[m][f][3]) << 16);
            }
    }
    __syncthreads();

    // ---- per-block KV partial: KV[64][64] = KphiT(64x128) @ V(128x64), waves 0..3
    float* partBlk = part + (long)blockIdx.x * 4160;
    if (w < 4) {
        f32x4 kv[4];
#pragma unroll
        for (int f = 0; f < 4; ++f) kv[f] = (f32x4){0.f, 0.f, 0.f, 0.f};
#pragma unroll
        for (int ks = 0; ks < 4; ++ks) {
            const int ko = ks * 32 + g * 8;
            bf16x8 a = *(const bf16x8*)(kT + (w * 16 + c) * TS + ko);
#pragma unroll
            for (int f = 0; f < 4; ++f) {
                bf16x8 b = *(const bf16x8*)(vT + (f * 16 + c) * TS + ko);
                kv[f] = __builtin_amdgcn_mfma_f32_16x16x32_bf16(a, b, kv[f], 0, 0, 0);
            }
        }
#pragma unroll
        for (int f = 0; f < 4; ++f)
#pragma unroll
            for (int reg = 0; reg < 4; ++reg)
                partBlk[(w * 16 + g * 4 + reg) * 64 + f * 16 + c] = kv[f][reg];
    }
    if (tid < 64) partBlk[4096 + tid] = ksum_lds[tid];
}

// -------------------------------------------------------------- reduce ----
// finals[e] += sum over a 128-block slice of partials; 8 slices x 65 blocks.
__global__ void la_reduce(const float* __restrict__ part, float* __restrict__ finals) {
    const int e  = (blockIdx.x % 65) * 64 + threadIdx.x;
    const int bs = blockIdx.x / 65;
    if (e < 4160) {
        float s = 0.f;
        const float* p = part + (long)bs * 128 * 4160 + e;
        for (int b = 0; b < 128; ++b) s += p[(long)b * 4160];
        atomicAdd(&finals[e], s);
    }
}

// ----------------------------------------------------------------- out ----
// out[i][:] = (Qphi[i] @ KV) / (Qphi[i].ksum + eps). BM=128, 4 waves.
__global__ __launch_bounds__(256) void la_out(
    const unsigned short* __restrict__ qphi, const float* __restrict__ finals,
    float* __restrict__ out)
{
    __shared__ __align__(16) unsigned short kvT[64 * 72];  // KV^T as bf16, stride 72
    __shared__ float ks_l[64];
    __shared__ float z_l[4][32];

    const int tid = threadIdx.x;
    const int w = tid >> 6, l = tid & 63, c = l & 15, g = l >> 4;

    // KV (f32, [k][j]) -> kvT[j][k] bf16
    const int e0 = tid << 4;
    const int kk = e0 >> 6, j0 = e0 & 63;
#pragma unroll
    for (int q = 0; q < 16; ++q) kvT[(j0 + q) * 72 + kk] = f2bf(finals[e0 + q]);
    if (tid < 64) ks_l[tid] = finals[4096 + tid];
    __syncthreads();

    const long rowBase = (long)blockIdx.x * 128 + w * 32;

    // A-frags straight from global Qphi (16B/lane, aligned)
    bf16x8 a[2][2];
#pragma unroll
    for (int m = 0; m < 2; ++m)
#pragma unroll
        for (int ks = 0; ks < 2; ++ks)
            a[m][ks] = *(const bf16x8*)(qphi + (rowBase + m * 16 + c) * DK + ks * 32 + g * 8);

    // denominator: Z for rows (c + 16m) of this wave's 32-row strip
#pragma unroll
    for (int m = 0; m < 2; ++m) {
        float den = 0.f;
#pragma unroll
        for (int ks = 0; ks < 2; ++ks)
#pragma unroll
            for (int i = 0; i < 8; ++i)
                den += bf2f((unsigned short)a[m][ks][i]) * ks_l[ks * 32 + g * 8 + i];
        den += __shfl_xor(den, 16);
        den += __shfl_xor(den, 32);
        if (l < 16) z_l[w][m * 16 + c] = 1.f / (den + 1e-8f);
    }

    f32x4 acc[2][4];
#pragma unroll
    for (int m = 0; m < 2; ++m)
#pragma unroll
        for (int f = 0; f < 4; ++f) acc[m][f] = (f32x4){0.f, 0.f, 0.f, 0.f};
#pragma unroll
    for (int ks = 0; ks < 2; ++ks)
#pragma unroll
        for (int f = 0; f < 4; ++f) {
            bf16x8 b = *(const bf16x8*)(kvT + (f * 16 + c) * 72 + ks * 32 + g * 8);
#pragma unroll
            for (int m = 0; m < 2; ++m)
                acc[m][f] = __builtin_amdgcn_mfma_f32_16x16x32_bf16(a[m][ks], b, acc[m][f], 0, 0, 0);
        }

#pragma unroll
    for (int m = 0; m < 2; ++m)
#pragma unroll
        for (int reg = 0; reg < 4; ++reg) {
            const int row16 = g * 4 + reg;
            const float z = z_l[w][m * 16 + row16];
#pragma unroll
            for (int f = 0; f < 4; ++f)
                out[(rowBase + m * 16 + row16) * DK + f * 16 + c] = acc[m][f][reg] * z;
        }
}

// -------------------------------------------------------------- launch ----
extern "C" void kernel_launch(void* const* d_in, const int* in_sizes, int n_in,
                              void* d_out, int out_size, void* d_ws, size_t ws_size,
                              hipStream_t stream) {
    const float* X  = (const float*)d_in[0];
    const float* Wq = (const float*)d_in[1];
    const float* Wk = (const float*)d_in[2];
    const float* Wv = (const float*)d_in[3];
    float* out = (float*)d_out;

    char* ws = (char*)d_ws;
    // workspace layout (bytes):
    //   qphi  bf16 [131072][64]  : 16,777,216
    //   wbfT  bf16 [192][512]    :    196,608
    //   part  f32  [1024][4160]  : 17,039,360
    //   finals f32 [4160]        :     16,640   (total ~34.0 MB)
    unsigned short* qphi  = (unsigned short*)ws;
    unsigned short* wbfT  = (unsigned short*)(ws + 16777216);
    float*          part  = (float*)(ws + 16777216 + 196608);
    float*          fin   = (float*)(ws + 16777216 + 196608 + 17039360);

    la_prep  <<<96,   1024, 0, stream>>>(Wq, Wk, Wv, wbfT, fin);
    la_main  <<<1024,  768, 0, stream>>>(X, wbfT, qphi, part);
    la_reduce<<<520,    64, 0, stream>>>(part, fin);
    la_out   <<<1024,  256, 0, stream>>>(qphi, fin, out);
}

// Round 6
// 396.877 us; speedup vs baseline: 1.0609x; 1.0609x over previous
//
#include <hip/hip_runtime.h>
#include <hip/hip_bf16.h>

#define N_ROWS 131072
#define D_IN   512
#define DK     64

typedef short bf16x8 __attribute__((ext_vector_type(8)));
typedef float f32x4  __attribute__((ext_vector_type(4)));

__device__ __forceinline__ unsigned short f2bf(float f) {
    union { float f; unsigned u; } v; v.f = f;
    unsigned r = v.u + 0x7FFFu + ((v.u >> 16) & 1u);   // RNE
    return (unsigned short)(r >> 16);
}
__device__ __forceinline__ float bf2f(unsigned short h) {
    union { unsigned u; float f; } v; v.u = ((unsigned)h) << 16;
    return v.f;
}
__device__ __forceinline__ float phi_f(float x) {
    return x > 0.f ? (x + 1.f) : __expf(x);   // elu(x)+1
}

// ---------------------------------------------------------------- prep ----
__global__ void la_prep(const float* __restrict__ Wq, const float* __restrict__ Wk,
                        const float* __restrict__ Wv, unsigned short* __restrict__ wbfT,
                        float* __restrict__ finals) {
    int idx = blockIdx.x * 1024 + threadIdx.x;
    if (idx < 4160) finals[idx] = 0.f;
    if (idx < 192 * 512) {
        int cc = idx >> 9;            // 0..191 output feature
        int k  = idx & 511;           // 0..511 input feature
        const float* W = (cc < 64) ? Wq : (cc < 128 ? Wk : Wv);
        wbfT[idx] = f2bf(W[k * DK + (cc & 63)]);
    }
}

// ---------------------------------------------------------------- main ----
// BM=128, BK=64, 12 waves = 4 row-groups x 3 sections (Q,K,V).
// v2: double-buffered LDS (X and W), reg-staged prefetch, ONE barrier per
// K-iteration. Pipeline per iter t:
//   1. ds_write tile t (regs, loaded at t-1) -> buf[t&1]
//   2. __syncthreads()
//   3. issue global loads for t+1 -> regs      (latency hides under step 4)
//   4. ds_read frags from buf[t&1]; 16 MFMA/wave
// Safety: reads of buf[p]@t complete before barrier(t+1) (lgkmcnt precedes
// MFMA); writes to buf[p]@t+2 occur after barrier(t+1).
#define XS 72    // X LDS row stride (bf16): 144 B = 9*16 -> 2-way max
#define WSR 72   // W LDS row stride
#define TS 136   // transposed KphiT/VT row stride: 272 B = 17*16

__global__ __launch_bounds__(768) void la_main(
    const float* __restrict__ X, const unsigned short* __restrict__ wbfT,
    unsigned short* __restrict__ qphi, float* __restrict__ part)
{
    __shared__ __align__(16) char smem[92160];
    __shared__ float ksum_lds[64];

    unsigned short* xsb[2] = { (unsigned short*)smem,
                               (unsigned short*)(smem + 18432) };
    unsigned short* wsb[2] = { (unsigned short*)(smem + 36864),
                               (unsigned short*)(smem + 64512) };
    unsigned short* kT = (unsigned short*)smem;             // [64][136] overlay
    unsigned short* vT = (unsigned short*)(smem + 17408);   // [64][136] overlay

    const int tid = threadIdx.x;
    const int w   = tid >> 6;
    const int l   = tid & 63;
    const int c   = l & 15;
    const int g   = l >> 4;
    const int sec = w % 3;         // 0=Q 1=K 2=V
    const int r   = w / 3;         // row group 0..3
    const long rowBase = (long)blockIdx.x * 128;

    if (tid < 64) ksum_lds[tid] = 0.f;

    f32x4 acc[2][4];
#pragma unroll
    for (int m = 0; m < 2; ++m)
#pragma unroll
        for (int f = 0; f < 4; ++f) acc[m][f] = (f32x4){0.f, 0.f, 0.f, 0.f};

    // staging registers (single live copy; rewritten each iter)
    float4 xr0, xr1, xr2, xr3;     // threads 0..511: X slots tid+512j
    float4 wr0, wr1;               // all threads:   W slots tid+768j

    const int xsl = tid;           // X slot base (valid when tid<512)
    const int xrl0 = (xsl) >> 4,          xc0 = (xsl) & 15;
    const int xrl1 = (xsl + 512) >> 4,    xc1 = (xsl + 512) & 15;
    const int xrl2 = (xsl + 1024) >> 4,   xc2 = (xsl + 1024) & 15;
    const int xrl3 = (xsl + 1536) >> 4,   xc3 = (xsl + 1536) & 15;
    const int wcc0 = tid >> 3,           wch0 = tid & 7;
    const int wcc1 = (tid + 768) >> 3,   wch1 = (tid + 768) & 7;

    // prologue: issue loads for kb=0
    {
        const int k0 = 0;
        if (tid < 512) {
            xr0 = *(const float4*)(X + (rowBase + xrl0) * D_IN + k0 + (xc0 << 2));
            xr1 = *(const float4*)(X + (rowBase + xrl1) * D_IN + k0 + (xc1 << 2));
            xr2 = *(const float4*)(X + (rowBase + xrl2) * D_IN + k0 + (xc2 << 2));
            xr3 = *(const float4*)(X + (rowBase + xrl3) * D_IN + k0 + (xc3 << 2));
        }
        wr0 = *(const float4*)(wbfT + wcc0 * D_IN + k0 + (wch0 << 3));
        wr1 = *(const float4*)(wbfT + wcc1 * D_IN + k0 + (wch1 << 3));
    }

#pragma unroll
    for (int kb = 0; kb < 8; ++kb) {
        unsigned short* xs  = xsb[kb & 1];
        unsigned short* wsm = wsb[kb & 1];
        // --- step 1: write tile kb from regs into buf[kb&1]
        if (tid < 512) {
            {   const unsigned u0 = (unsigned)f2bf(xr0.x) | ((unsigned)f2bf(xr0.y) << 16);
                const unsigned u1 = (unsigned)f2bf(xr0.z) | ((unsigned)f2bf(xr0.w) << 16);
                *(uint2*)(xs + xrl0 * XS + (xc0 << 2)) = make_uint2(u0, u1); }
            {   const unsigned u0 = (unsigned)f2bf(xr1.x) | ((unsigned)f2bf(xr1.y) << 16);
                const unsigned u1 = (unsigned)f2bf(xr1.z) | ((unsigned)f2bf(xr1.w) << 16);
                *(uint2*)(xs + xrl1 * XS + (xc1 << 2)) = make_uint2(u0, u1); }
            {   const unsigned u0 = (unsigned)f2bf(xr2.x) | ((unsigned)f2bf(xr2.y) << 16);
                const unsigned u1 = (unsigned)f2bf(xr2.z) | ((unsigned)f2bf(xr2.w) << 16);
                *(uint2*)(xs + xrl2 * XS + (xc2 << 2)) = make_uint2(u0, u1); }
            {   const unsigned u0 = (unsigned)f2bf(xr3.x) | ((unsigned)f2bf(xr3.y) << 16);
                const unsigned u1 = (unsigned)f2bf(xr3.z) | ((unsigned)f2bf(xr3.w) << 16);
                *(uint2*)(xs + xrl3 * XS + (xc3 << 2)) = make_uint2(u0, u1); }
        }
        *(float4*)(wsm + wcc0 * WSR + (wch0 << 3)) = wr0;
        *(float4*)(wsm + wcc1 * WSR + (wch1 << 3)) = wr1;
        // --- step 2
        __syncthreads();
        // --- step 3: prefetch tile kb+1
        if (kb < 7) {
            const int k0 = (kb + 1) * 64;
            if (tid < 512) {
                xr0 = *(const float4*)(X + (rowBase + xrl0) * D_IN + k0 + (xc0 << 2));
                xr1 = *(const float4*)(X + (rowBase + xrl1) * D_IN + k0 + (xc1 << 2));
                xr2 = *(const float4*)(X + (rowBase + xrl2) * D_IN + k0 + (xc2 << 2));
                xr3 = *(const float4*)(X + (rowBase + xrl3) * D_IN + k0 + (xc3 << 2));
            }
            wr0 = *(const float4*)(wbfT + wcc0 * D_IN + k0 + (wch0 << 3));
            wr1 = *(const float4*)(wbfT + wcc1 * D_IN + k0 + (wch1 << 3));
        }
        // --- step 4: compute on buf[kb&1]
#pragma unroll
        for (int ks = 0; ks < 2; ++ks) {
            const int ko = ks * 32 + g * 8;
            bf16x8 a[2], b[4];
#pragma unroll
            for (int m = 0; m < 2; ++m)
                a[m] = *(const bf16x8*)(xs + (r * 32 + m * 16 + c) * XS + ko);
#pragma unroll
            for (int f = 0; f < 4; ++f)
                b[f] = *(const bf16x8*)(wsm + (sec * 64 + f * 16 + c) * WSR + ko);
#pragma unroll
            for (int m = 0; m < 2; ++m)
#pragma unroll
                for (int f = 0; f < 4; ++f)
                    acc[m][f] = __builtin_amdgcn_mfma_f32_16x16x32_bf16(a[m], b[f], acc[m][f], 0, 0, 0);
        }
    }
    __syncthreads();   // all LDS reads done before kT/vT overlay writes

    // ---- epilogue: C/D frag mapping col = c + 16f, row = 32r + 16m + 4g + reg
    if (sec == 0) {
#pragma unroll
        for (int m = 0; m < 2; ++m)
#pragma unroll
            for (int f = 0; f < 4; ++f)
#pragma unroll
                for (int reg = 0; reg < 4; ++reg) {
                    const long row = rowBase + r * 32 + m * 16 + g * 4 + reg;
                    qphi[row * DK + f * 16 + c] = f2bf(phi_f(acc[m][f][reg]));
                }
    } else if (sec == 1) {
        float s[4] = {0.f, 0.f, 0.f, 0.f};
#pragma unroll
        for (int m = 0; m < 2; ++m)
#pragma unroll
            for (int f = 0; f < 4; ++f) {
                float p0 = phi_f(acc[m][f][0]), p1 = phi_f(acc[m][f][1]);
                float p2 = phi_f(acc[m][f][2]), p3 = phi_f(acc[m][f][3]);
                s[f] += p0 + p1 + p2 + p3;
                const int col = f * 16 + c;
                const int row0 = r * 32 + m * 16 + g * 4;
                *(unsigned*)(kT + col * TS + row0)     = (unsigned)f2bf(p0) | ((unsigned)f2bf(p1) << 16);
                *(unsigned*)(kT + col * TS + row0 + 2) = (unsigned)f2bf(p2) | ((unsigned)f2bf(p3) << 16);
            }
#pragma unroll
        for (int f = 0; f < 4; ++f) {
            s[f] += __shfl_xor(s[f], 16);
            s[f] += __shfl_xor(s[f], 32);
        }
        if (l < 16)
#pragma unroll
            for (int f = 0; f < 4; ++f) atomicAdd(&ksum_lds[f * 16 + c], s[f]);
    } else {
#pragma unroll
        for (int m = 0; m < 2; ++m)
#pragma unroll
            for (int f = 0; f < 4; ++f) {
                const int col = f * 16 + c;
                const int row0 = r * 32 + m * 16 + g * 4;
                *(unsigned*)(vT + col * TS + row0) =
                    (unsigned)f2bf(acc[m][f][0]) | ((unsigned)f2bf(acc[m][f][1]) << 16);
                *(unsigned*)(vT + col * TS + row0 + 2) =
                    (unsigned)f2bf(acc[m][f][2]) | ((unsigned)f2bf(acc[m][f][3]) << 16);
            }
    }
    __syncthreads();

    // ---- per-block KV partial: KV[64][64] = KphiT(64x128) @ V(128x64)
    float* partBlk = part + (long)blockIdx.x * 4160;
    if (w < 4) {
        f32x4 kv[4];
#pragma unroll
        for (int f = 0; f < 4; ++f) kv[f] = (f32x4){0.f, 0.f, 0.f, 0.f};
#pragma unroll
        for (int ks = 0; ks < 4; ++ks) {
            const int ko = ks * 32 + g * 8;
            bf16x8 a = *(const bf16x8*)(kT + (w * 16 + c) * TS + ko);
#pragma unroll
            for (int f = 0; f < 4; ++f) {
                bf16x8 b = *(const bf16x8*)(vT + (f * 16 + c) * TS + ko);
                kv[f] = __builtin_amdgcn_mfma_f32_16x16x32_bf16(a, b, kv[f], 0, 0, 0);
            }
        }
#pragma unroll
        for (int f = 0; f < 4; ++f)
#pragma unroll
            for (int reg = 0; reg < 4; ++reg)
                partBlk[(w * 16 + g * 4 + reg) * 64 + f * 16 + c] = kv[f][reg];
    }
    if (tid < 64) partBlk[4096 + tid] = ksum_lds[tid];
}

// -------------------------------------------------------------- reduce ----
__global__ void la_reduce(const float* __restrict__ part, float* __restrict__ finals) {
    const int e  = (blockIdx.x % 65) * 64 + threadIdx.x;
    const int bs = blockIdx.x / 65;
    if (e < 4160) {
        float s = 0.f;
        const float* p = part + (long)bs * 128 * 4160 + e;
        for (int b = 0; b < 128; ++b) s += p[(long)b * 4160];
        atomicAdd(&finals[e], s);
    }
}

// ----------------------------------------------------------------- out ----
__global__ __launch_bounds__(256) void la_out(
    const unsigned short* __restrict__ qphi, const float* __restrict__ finals,
    float* __restrict__ out)
{
    __shared__ __align__(16) unsigned short kvT[64 * 72];  // KV^T bf16, stride 72
    __shared__ float ks_l[64];
    __shared__ float z_l[4][32];

    const int tid = threadIdx.x;
    const int w = tid >> 6, l = tid & 63, c = l & 15, g = l >> 4;

    const int e0 = tid << 4;
    const int kk = e0 >> 6, j0 = e0 & 63;
#pragma unroll
    for (int q = 0; q < 16; ++q) kvT[(j0 + q) * 72 + kk] = f2bf(finals[e0 + q]);
    if (tid < 64) ks_l[tid] = finals[4096 + tid];
    __syncthreads();

    const long rowBase = (long)blockIdx.x * 128 + w * 32;

    bf16x8 a[2][2];
#pragma unroll
    for (int m = 0; m < 2; ++m)
#pragma unroll
        for (int ks = 0; ks < 2; ++ks)
            a[m][ks] = *(const bf16x8*)(qphi + (rowBase + m * 16 + c) * DK + ks * 32 + g * 8);

#pragma unroll
    for (int m = 0; m < 2; ++m) {
        float den = 0.f;
#pragma unroll
        for (int ks = 0; ks < 2; ++ks)
#pragma unroll
            for (int i = 0; i < 8; ++i)
                den += bf2f((unsigned short)a[m][ks][i]) * ks_l[ks * 32 + g * 8 + i];
        den += __shfl_xor(den, 16);
        den += __shfl_xor(den, 32);
        if (l < 16) z_l[w][m * 16 + c] = 1.f / (den + 1e-8f);
    }

    f32x4 acc[2][4];
#pragma unroll
    for (int m = 0; m < 2; ++m)
#pragma unroll
        for (int f = 0; f < 4; ++f) acc[m][f] = (f32x4){0.f, 0.f, 0.f, 0.f};
#pragma unroll
    for (int ks = 0; ks < 2; ++ks)
#pragma unroll
        for (int f = 0; f < 4; ++f) {
            bf16x8 b = *(const bf16x8*)(kvT + (f * 16 + c) * 72 + ks * 32 + g * 8);
#pragma unroll
            for (int m = 0; m < 2; ++m)
                acc[m][f] = __builtin_amdgcn_mfma_f32_16x16x32_bf16(a[m][ks], b, acc[m][f], 0, 0, 0);
        }

#pragma unroll
    for (int m = 0; m < 2; ++m)
#pragma unroll
        for (int reg = 0; reg < 4; ++reg) {
            const int row16 = g * 4 + reg;
            const float z = z_l[w][m * 16 + row16];
#pragma unroll
            for (int f = 0; f < 4; ++f)
                out[(rowBase + m * 16 + row16) * DK + f * 16 + c] = acc[m][f][reg] * z;
        }
}

// -------------------------------------------------------------- launch ----
extern "C" void kernel_launch(void* const* d_in, const int* in_sizes, int n_in,
                              void* d_out, int out_size, void* d_ws, size_t ws_size,
                              hipStream_t stream) {
    const float* X  = (const float*)d_in[0];
    const float* Wq = (const float*)d_in[1];
    const float* Wk = (const float*)d_in[2];
    const float* Wv = (const float*)d_in[3];
    float* out = (float*)d_out;

    char* ws = (char*)d_ws;
    unsigned short* qphi  = (unsigned short*)ws;
    unsigned short* wbfT  = (unsigned short*)(ws + 16777216);
    float*          part  = (float*)(ws + 16777216 + 196608);
    float*          fin   = (float*)(ws + 16777216 + 196608 + 17039360);

    la_prep  <<<96,   1024, 0, stream>>>(Wq, Wk, Wv, wbfT, fin);
    la_main  <<<1024,  768, 0, stream>>>(X, wbfT, qphi, part);
    la_reduce<<<520,    64, 0, stream>>>(part, fin);
    la_out   <<<1024,  256, 0, stream>>>(qphi, fin, out);
}